// Round 4
// baseline (299.535 us; speedup 1.0000x reference)
//
#include <hip/hip_runtime.h>
#include <math.h>

// Causal depthwise conv1d K=4 + SiLU. x (B=4, T=4096, C=2048) fp32, kernel (4, C) fp32.
// y[b,t,c] = silu( sum_j k[j,c] * x[b,t-j,c] ), zero-padded; next_cache = x[:, T-3:, :].
//
// R3 post-mortem: sliding-window kernel stuck at 84us, VGPR=32 -> compiler serialized
// the "4 loads in flight" (weights+window ate the register budget under launch_bounds).
// R4: flat elementwise mapping, 1 thread = 1 output, 4 independent tap loads (L2/L3
// absorb the 4x read amplification), no register carry, cache-copy fused in.

#define B_   4
#define T_   4096
#define C_   2048
#define K_   4
#define C4_  (C_ / 4)   // 512 float4 groups per row

typedef float nat_float4 __attribute__((ext_vector_type(4)));

__device__ __forceinline__ float silu_f(float v) {
    return v * __frcp_rn(1.f + __expf(-v));
}

__device__ __forceinline__ void store_nt(float4* p, const float4& v) {
    nat_float4 nv = { v.x, v.y, v.z, v.w };
    __builtin_nontemporal_store(nv, reinterpret_cast<nat_float4*>(p));
}

__global__ __launch_bounds__(256) void dwconv_silu_flat(
    const float4* __restrict__ x,      // [B, T, C4]
    const float4* __restrict__ kern,   // [K, C4]
    float4* __restrict__ y,            // [B, T, C4]
    float4* __restrict__ cache)        // [B, 3, C4]
{
    const int i  = blockIdx.x * 256 + threadIdx.x;   // 0 .. B*T*C4-1
    const int c4 = i & (C4_ - 1);
    const int t  = (i >> 9) & (T_ - 1);              // wave-uniform (64 lanes span c4)
    const int b  = i >> 21;

    const float4 zero = make_float4(0.f, 0.f, 0.f, 0.f);

    // 4 independent tap loads — maximal MLP, no serial window chain.
    float4 x0, x1, x2, x3;
    x0 = x[i];
    if (t >= 3) {                       // wave-uniform branch, true except 3 rows/batch
        x1 = x[i - 1 * C4_];
        x2 = x[i - 2 * C4_];
        x3 = x[i - 3 * C4_];
    } else {
        x1 = (t >= 1) ? x[i - 1 * C4_] : zero;
        x2 = (t >= 2) ? x[i - 2 * C4_] : zero;
        x3 = zero;
    }

    const float4 k0 = kern[0 * C4_ + c4];
    const float4 k1 = kern[1 * C4_ + c4];
    const float4 k2 = kern[2 * C4_ + c4];
    const float4 k3 = kern[3 * C4_ + c4];

    float4 r;
    r.x = fmaf(k0.x, x0.x, fmaf(k1.x, x1.x, fmaf(k2.x, x2.x, k3.x * x3.x)));
    r.y = fmaf(k0.y, x0.y, fmaf(k1.y, x1.y, fmaf(k2.y, x2.y, k3.y * x3.y)));
    r.z = fmaf(k0.z, x0.z, fmaf(k1.z, x1.z, fmaf(k2.z, x2.z, k3.z * x3.z)));
    r.w = fmaf(k0.w, x0.w, fmaf(k1.w, x1.w, fmaf(k2.w, x2.w, k3.w * x3.w)));
    r.x = silu_f(r.x); r.y = silu_f(r.y); r.z = silu_f(r.z); r.w = silu_f(r.w);

    store_nt(&y[i], r);                 // y is write-once: don't pollute L2

    // Fused next_cache = x[:, T-3:, :]
    if (t >= T_ - 3) {
        cache[((size_t)b * 3 + (t - (T_ - 3))) * C4_ + c4] = x0;
    }
}

extern "C" void kernel_launch(void* const* d_in, const int* in_sizes, int n_in,
                              void* d_out, int out_size, void* d_ws, size_t ws_size,
                              hipStream_t stream)
{
    const float4* x    = (const float4*)d_in[0];
    const float4* kern = (const float4*)d_in[1];
    float*        out  = (float*)d_out;

    float4* y     = (float4*)out;
    float4* cache = (float4*)(out + (size_t)B_ * T_ * C_);

    const int total = B_ * T_ * C4_;     // 8,388,608 threads
    dwconv_silu_flat<<<total / 256, 256, 0, stream>>>(x, kern, y, cache);
}